// Round 4
// baseline (1811.378 us; speedup 1.0000x reference)
//
#include <hip/hip_runtime.h>
#include <hip/hip_bf16.h>

typedef __hip_bfloat16 bf16;
#define DEV __device__ __forceinline__

// ---------------- problem constants ----------------
// N=16, C=64, H=W=160, S=25600, expanded channels 192, windows {1,3,5}
// Inputs fp32 (confirmed round 3: bf16 reads -> NaN, fp32 reads -> finite).
// Output fp32 (reference output dtype; round-3 error pattern = bf16 written
// into an fp32-read buffer).

// fp32 scratch layout (offsets in floats)
constexpr int FO_Q     = 0;         // raw softmax logits, per-window concat (1239104)
constexpr int FO_SMAP  = 1239104;   // sigmoid spatial gate (1239104)
constexpr int FO_XM    = 2478208;   // per-(b,c') channel sums (560*64)
constexpr int FO_T     = 2514048;   // per-(b,c') q-weighted sums (560*64)
constexpr int FO_SIGA  = 2549888;   // per-(b,c') channel gate sigmoid(zn) (560*64)
constexpr int FO_G     = 2585728;   // per-(b,c') spatial-branch weights (560*64)
constexpr int FO_BM    = 2621568;   // per-b logit max (560)
constexpr int FO_BINV  = 2622128;   // per-b 1/sum(exp) (560)
constexpr int FO_GB    = 2622688;   // per-b spatial bias term (560)
constexpr int FO_EXPT  = 2623248;   // exp_w transposed [c*192+o] (12288)
constexpr int FO_EXPB  = 2635536;   // exp_b fp32 (192)
constexpr int FO_WBIGT = 2635728;   // combined final weight [k*64+f], k<256 (16384)
constexpr int FO_BCOMB = 2652112;   // combined final bias (64)
constexpr int FB_SIZE  = 2652176;

// Static device storage (d_ws size is not trusted).
__device__ unsigned short g_ex_u[78643200]; // 16*192*25600 bf16
__device__ float          g_fb[FB_SIZE];

template<int WIN> struct WP;
template<> struct WP<1> { static constexpr int WI=0, SH=160, KH=160, K=25600, P=1,  B=16,  QOFF=0,      BOFF=0,   CHUNKS=13; };
template<> struct WP<3> { static constexpr int WI=1, SH=53,  KH=54,  K=2916,  P=9,  B=144, QOFF=409600, BOFF=16,  CHUNKS=2;  };
template<> struct WP<5> { static constexpr int WI=2, SH=32,  KH=32,  K=1024,  P=25, B=400, QOFF=829504, BOFF=160, CHUNKS=1;  };

// psa-space (c',s') walk: element f = b_local*CK + c'*K + s' maps to original
// (c, kidx, p) with f = (c*K + kidx)*P + p.
template<int WIN> DEV void decomp(int f, int& c, int& kidx, int& p) {
  constexpr int P = WP<WIN>::P, K = WP<WIN>::K;
  int m;
  if constexpr (P == 1) { p = 0; m = f; }
  else { m = f / P; p = f - m * P; }
  c = m / K; kidx = m - c * K;
}

template<int WIN> DEV void stepK(int& c, int& kidx, int& p) {  // f += K
  constexpr int K = WP<WIN>::K, P = WP<WIN>::P;
  if constexpr (P == 1) { kidx += K; }
  else {
    constexpr int KMP = K % P, KDP = K / P;
    if constexpr (KMP == 0) { kidx += KDP; }
    else { p += KMP; if (p >= P) { p -= P; kidx += KDP + 1; } else kidx += KDP; }
  }
  if (kidx >= K) { kidx -= K; ++c; }
}

template<int WIN> DEV int pix(int kidx, int p) {
  constexpr int KH = WP<WIN>::KH, SH = WP<WIN>::SH;
  if constexpr (WIN == 1) return kidx;
  int ki = kidx / KH, kj = kidx - ki * KH;
  int ph = p / WIN,  pw = p - ph * WIN;
  return (ph * SH + ki) * 160 + pw * SH + kj;
}

// ---------------- k_prep: weight precompute + zero xm/t ----------------
__global__ __launch_bounds__(256)
void k_prep(const float* __restrict__ exp_w, const float* __restrict__ exp_b,
            const float* __restrict__ res_w, const float* __restrict__ res_b,
            const float* __restrict__ fus_w, const float* __restrict__ fus_b) {
  float* fb = g_fb;
  int gt = blockIdx.x * 256 + threadIdx.x;
  if (gt < 12288) {                       // Wcomb[f][oc] = sum_o fus[f][o]*res[o][oc]
    int oc = gt % 192, f = gt / 192;
    float a = 0.f;
    for (int o = 0; o < 64; ++o)
      a += fus_w[f*64+o] * res_w[o*192+oc];
    fb[FO_WBIGT + oc*64 + f] = a;
  } else if (gt < 16384) {                // rows 192..255: fus_w
    int t2 = gt - 12288; int o = t2 % 64, f = t2 / 64;
    fb[FO_WBIGT + (192+o)*64 + f] = fus_w[f*64+o];
  } else if (gt < 16448) {                // bcomb
    int f = gt - 16384;
    float a = fus_b[f];
    for (int o = 0; o < 64; ++o)
      a += fus_w[f*64+o] * res_b[o];
    fb[FO_BCOMB + f] = a;
  } else if (gt < 28736) {                // expT[c*192+o] = exp_w[o][c]
    int t3 = gt - 16448; int o = t3 % 192, c = t3 / 192;
    fb[FO_EXPT + c*192 + o] = exp_w[o*64+c];
  } else if (gt < 28928) {
    int o = gt - 28736;
    fb[FO_EXPB + o] = exp_b[o];
  } else if (gt < 28928 + 71680) {        // zero xm and t (contiguous)
    fb[FO_XM + gt - 28928] = 0.f;
  }
}

// ---------------- k_ex: ex = conv1x1(x, exp_w, exp_b), bf16 out ----------------
__global__ __launch_bounds__(256)
void k_ex(const float* __restrict__ x) {
  const float* fb = g_fb;
  bf16* ex = (bf16*)g_ex_u;
  __shared__ float xs[64*64];
  int blk = blockIdx.x; int n = blk / 400; int s0 = (blk % 400) * 64;
  int tid = threadIdx.x;
  for (int e = tid; e < 4096; e += 256) {
    int c = e >> 6, px = e & 63;
    xs[e] = x[(n*64 + c)*25600 + s0 + px];
  }
  __syncthreads();
  int px = tid & 63;
  int o0 = __builtin_amdgcn_readfirstlane((tid >> 6) * 48);
  float acc[48];
#pragma unroll
  for (int j = 0; j < 48; ++j) acc[j] = fb[FO_EXPB + o0 + j];
  const float* wT = fb + FO_EXPT;
  for (int c = 0; c < 64; ++c) {
    float xv = xs[(c << 6) + px];
    const float* wr = wT + c*192 + o0;
#pragma unroll
    for (int j = 0; j < 48; ++j) acc[j] += wr[j] * xv;
  }
  bf16* eo = ex + (size_t)(n*192 + o0)*25600 + s0 + px;
#pragma unroll
  for (int j = 0; j < 48; ++j) eo[(size_t)j*25600] = __float2bfloat16(acc[j]);
}

// ---------------- k_logit: per-(b,s') channel dot with ch_wq ----------------
template<int WIN> __global__ __launch_bounds__(256)
void k_logit(const float* __restrict__ chq_w, const float* __restrict__ chq_b) {
  using W = WP<WIN>;
  constexpr int K = W::K, P = W::P, CK = 64*K, WI = W::WI, QOFF = W::QOFF, CH = W::CHUNKS;
  float* fb = g_fb;
  const bf16* ex = (const bf16*)g_ex_u;
  __shared__ float wq[64]; __shared__ float wqb;
  int tid = threadIdx.x;
  if (tid < 64) wq[tid] = chq_w[tid];
  if (tid == 64) wqb = chq_b[0];
  __syncthreads();
  int blk = blockIdx.x; int bi = blk / CH; int ch = blk - bi*CH;
  int n = bi / P, bl = bi - n*P;
  int send = ((ch+1)*2048 < K) ? (ch+1)*2048 : K;
  const bf16* exn = ex + (size_t)(n*192 + WI*64)*25600;
  float* qout = fb + FO_Q + QOFF + (size_t)bi*K;
  for (int sp = ch*2048 + tid; sp < send; sp += 256) {
    int f = bl*CK + sp;
    int c, kidx, p; decomp<WIN>(f, c, kidx, p);
    float acc = 0.f;
#pragma unroll 8
    for (int cp = 0; cp < 64; ++cp) {
      acc += wq[cp] * __bfloat162float(exn[c*25600 + pix<WIN>(kidx, p)]);
      stepK<WIN>(c, kidx, p);
    }
    qout[sp] = acc + wqb;
  }
}

// ---------------- k_xm: per-(b,c') sums over s' ----------------
template<int WIN> __global__ __launch_bounds__(256)
void k_xm() {
  using W = WP<WIN>;
  constexpr int K = W::K, P = W::P, CK = 64*K, WI = W::WI, BOFF = W::BOFF, CH = W::CHUNKS;
  float* fb = g_fb;
  const bf16* ex = (const bf16*)g_ex_u;
  int tid = threadIdx.x; int lane = tid & 63; int c0 = (tid >> 6) * 16;
  int blk = blockIdx.x; int bi = blk / CH; int ch = blk - bi*CH;
  int n = bi / P, bl = bi - n*P; int bg = BOFF + bi;
  int send = ((ch+1)*2048 < K) ? (ch+1)*2048 : K;
  const bf16* exn = ex + (size_t)(n*192 + WI*64)*25600;
  float part[16];
#pragma unroll
  for (int j = 0; j < 16; ++j) part[j] = 0.f;
  for (int sp = ch*2048 + lane; sp < send; sp += 64) {
    int f = bl*CK + c0*K + sp;
    int c, kidx, p; decomp<WIN>(f, c, kidx, p);
#pragma unroll
    for (int j = 0; j < 16; ++j) {
      part[j] += __bfloat162float(exn[c*25600 + pix<WIN>(kidx, p)]);
      stepK<WIN>(c, kidx, p);
    }
  }
#pragma unroll
  for (int j = 0; j < 16; ++j) {
    float v = part[j];
    for (int off = 32; off; off >>= 1) v += __shfl_xor(v, off, 64);
    if (lane == 0) atomicAdd(&fb[FO_XM + bg*64 + c0 + j], v);
  }
}

// ---------------- k_bstats: per-b softmax stats + spatial branch ----------------
__global__ __launch_bounds__(256)
void k_bstats(const float* __restrict__ spq_w, const float* __restrict__ spq_b,
              const float* __restrict__ spv_w, const float* __restrict__ spv_b) {
  float* fb = g_fb;
  __shared__ float red[256]; __shared__ float sqs[32]; __shared__ float swq[32];
  int bg = blockIdx.x, tid = threadIdx.x;
  int Kk, qo, bi;
  if (bg < 16)       { Kk = 25600; qo = 0;      bi = bg;       }
  else if (bg < 160) { Kk = 2916;  qo = 409600; bi = bg - 16;  }
  else               { Kk = 1024;  qo = 829504; bi = bg - 160; }
  const float* lg = fb + FO_Q + qo + (size_t)bi*Kk;
  float m = -1e30f;
  for (int s = tid; s < Kk; s += 256) m = fmaxf(m, lg[s]);
  red[tid] = m; __syncthreads();
  for (int st = 128; st; st >>= 1) { if (tid < st) red[tid] = fmaxf(red[tid], red[tid+st]); __syncthreads(); }
  float M = red[0]; __syncthreads();
  float ss = 0.f;
  for (int s = tid; s < Kk; s += 256) ss += __expf(lg[s] - M);
  red[tid] = ss; __syncthreads();
  for (int st = 128; st; st >>= 1) { if (tid < st) red[tid] += red[tid+st]; __syncthreads(); }
  if (tid == 0) { fb[FO_BM + bg] = M; fb[FO_BINV + bg] = 1.f / red[0]; }
  // spatial branch: sq from channel means, softmax over 32, then g
  const float* xm_b = fb + FO_XM + bg*64;
  float rK = 1.f / (float)Kk;
  if (tid < 32) {
    float a = spq_b[tid];
    for (int c = 0; c < 64; ++c)
      a += spq_w[tid*64 + c] * (xm_b[c] * rK);
    sqs[tid] = a;
  }
  __syncthreads();
  if (tid == 0) {
    float mx = -1e30f;
    for (int o = 0; o < 32; ++o) mx = fmaxf(mx, sqs[o]);
    float z = 0.f;
    for (int o = 0; o < 32; ++o) { float e = __expf(sqs[o] - mx); swq[o] = e; z += e; }
    float rz = 1.f / z;
    for (int o = 0; o < 32; ++o) swq[o] *= rz;
  }
  __syncthreads();
  if (tid < 64) {
    float a = 0.f;
    for (int o = 0; o < 32; ++o) a += swq[o] * spv_w[o*64 + tid];
    fb[FO_G + bg*64 + tid] = a;
  }
  if (tid == 64) {
    float gb = 0.f;
    for (int o = 0; o < 32; ++o) gb += swq[o] * spv_b[o];
    fb[FO_GB + bg] = gb;
  }
}

// ---------------- k_t: t[b,c'] = sum_s q[s] X[c',s] ----------------
template<int WIN> __global__ __launch_bounds__(256)
void k_t() {
  using W = WP<WIN>;
  constexpr int K = W::K, P = W::P, CK = 64*K, WI = W::WI, QOFF = W::QOFF, BOFF = W::BOFF, CH = W::CHUNKS;
  float* fb = g_fb;
  const bf16* ex = (const bf16*)g_ex_u;
  int tid = threadIdx.x; int lane = tid & 63; int c0 = (tid >> 6) * 16;
  int blk = blockIdx.x; int bi = blk / CH; int ch = blk - bi*CH;
  int n = bi / P, bl = bi - n*P; int bg = BOFF + bi;
  int send = ((ch+1)*2048 < K) ? (ch+1)*2048 : K;
  const bf16* exn = ex + (size_t)(n*192 + WI*64)*25600;
  const float* qin = fb + FO_Q + QOFF + (size_t)bi*K;
  float M = fb[FO_BM + bg], inv = fb[FO_BINV + bg];
  float part[16];
#pragma unroll
  for (int j = 0; j < 16; ++j) part[j] = 0.f;
  for (int sp = ch*2048 + lane; sp < send; sp += 64) {
    float qv = __expf(qin[sp] - M) * inv;
    int f = bl*CK + c0*K + sp;
    int c, kidx, p; decomp<WIN>(f, c, kidx, p);
#pragma unroll
    for (int j = 0; j < 16; ++j) {
      part[j] += qv * __bfloat162float(exn[c*25600 + pix<WIN>(kidx, p)]);
      stepK<WIN>(c, kidx, p);
    }
  }
#pragma unroll
  for (int j = 0; j < 16; ++j) {
    float v = part[j];
    for (int off = 32; off; off >>= 1) v += __shfl_xor(v, off, 64);
    if (lane == 0) atomicAdd(&fb[FO_T + bg*64 + c0 + j], v);
  }
}

// ---------------- k_smap: smap[b,s'] = sigmoid(sum_c g[c] X[c,s'] + gb) ----------------
template<int WIN> __global__ __launch_bounds__(256)
void k_smap() {
  using W = WP<WIN>;
  constexpr int K = W::K, P = W::P, CK = 64*K, WI = W::WI, QOFF = W::QOFF, BOFF = W::BOFF, CH = W::CHUNKS;
  float* fb = g_fb;
  const bf16* ex = (const bf16*)g_ex_u;
  __shared__ float gs[64]; __shared__ float gbs;
  int tid = threadIdx.x;
  int blk = blockIdx.x; int bi = blk / CH; int ch = blk - bi*CH;
  int n = bi / P, bl = bi - n*P; int bg = BOFF + bi;
  if (tid < 64) gs[tid] = fb[FO_G + bg*64 + tid];
  if (tid == 64) gbs = fb[FO_GB + bg];
  __syncthreads();
  int send = ((ch+1)*2048 < K) ? (ch+1)*2048 : K;
  const bf16* exn = ex + (size_t)(n*192 + WI*64)*25600;
  float* so = fb + FO_SMAP + QOFF + (size_t)bi*K;
  for (int sp = ch*2048 + tid; sp < send; sp += 256) {
    int f = bl*CK + sp;
    int c, kidx, p; decomp<WIN>(f, c, kidx, p);
    float acc = gbs;
#pragma unroll 8
    for (int cp = 0; cp < 64; ++cp) {
      acc += gs[cp] * __bfloat162float(exn[c*25600 + pix<WIN>(kidx, p)]);
      stepK<WIN>(c, kidx, p);
    }
    so[sp] = 1.f / (1.f + __expf(-acc));
  }
}

// ---------------- k_zln: wz -> z -> LayerNorm -> sigA ----------------
__global__ __launch_bounds__(64)
void k_zln(const float* __restrict__ chv_w, const float* __restrict__ chv_b,
           const float* __restrict__ chz_w, const float* __restrict__ chz_b,
           const float* __restrict__ ln_g,  const float* __restrict__ ln_b) {
  float* fb = g_fb;
  __shared__ float wzs[32]; __shared__ float zsh[64]; __shared__ float mom[2];
  int bg = blockIdx.x, tid = threadIdx.x;
  const float* t_b = fb + FO_T + bg*64;
  if (tid < 32) {
    float a = chv_b[tid];
    for (int c = 0; c < 64; ++c)
      a += chv_w[tid*64 + c] * t_b[c];
    wzs[tid] = a;
  }
  __syncthreads();
  float zv = chz_b[tid];
  for (int o = 0; o < 32; ++o)
    zv += chz_w[tid*32 + o] * wzs[o];
  zsh[tid] = zv;
  __syncthreads();
  if (tid == 0) {
    float mu = 0.f;
    for (int j = 0; j < 64; ++j) mu += zsh[j];
    mu *= (1.f/64.f);
    float m2 = 0.f;
    for (int j = 0; j < 64; ++j) { float d = zsh[j] - mu; m2 += d*d; }
    m2 *= (1.f/64.f);
    mom[0] = mu; mom[1] = rsqrtf(m2 + 1e-5f);
  }
  __syncthreads();
  float zn = (zv - mom[0]) * mom[1] * ln_g[tid] + ln_b[tid];
  fb[FO_SIGA + bg*64 + tid] = 1.f / (1.f + __expf(-zn));
}

// ---------------- k_final: gates -> cat -> fused double conv ----------------
template<int WIN> DEV void gate_rows(int n, int h, int w, int px,
                                     const bf16* __restrict__ ex,
                                     const float* __restrict__ fb, float* ext) {
  using W = WP<WIN>;
  constexpr int SH = W::SH, KH = W::KH, K = W::K, P = W::P, WI = W::WI,
                QOFF = W::QOFF, BOFF = W::BOFF;
  constexpr int CK = 64*K, KP = K*P;
  int s = h*160 + w;
  int phmin = (h >= KH) ? (h - KH)/SH + 1 : 0;
  int phmax = (WIN-1 < h/SH) ? WIN-1 : h/SH;
  int pwmin = (w >= KH) ? (w - KH)/SH + 1 : 0;
  int pwmax = (WIN-1 < w/SH) ? WIN-1 : w/SH;
  int base0s[4]; int np = 0;
  for (int ph = phmin; ph <= phmax; ++ph)
    for (int pw = pwmin; pw <= pwmax; ++pw) {
      int ki = h - ph*SH, kj = w - pw*SH;
      base0s[np++] = (ki*KH + kj)*P + ph*WIN + pw;
    }
  float rc = 1.f / (float)np;
  const float* siga = fb + FO_SIGA + (size_t)(BOFF + n*P)*64;
  const float* smap = fb + FO_SMAP + QOFF + (size_t)(n*P)*K;
  const bf16* exr = ex + (size_t)(n*192 + WI*64)*25600 + s;
  for (int c = 0; c < 64; ++c) {
    float gsum = 0.f;
    for (int t = 0; t < np; ++t) {
      int f = c*KP + base0s[t];
      int bl = f / CK; int r = f - bl*CK;
      int cp = r / K;  int sp = r - cp*K;
      gsum += siga[bl*64 + cp] + smap[(size_t)bl*K + sp];
    }
    float exv = __bfloat162float(exr[(size_t)c*25600]);
    ext[(WI*64 + c)*64 + px] = exv * (1.f + gsum * rc);
  }
}

__global__ __launch_bounds__(256)
void k_final(const float* __restrict__ x, float* __restrict__ out) {
  const float* fb = g_fb;
  const bf16* ex = (const bf16*)g_ex_u;
  __shared__ float ext[256*64];
  int blk = blockIdx.x; int n = blk / 400; int s0 = (blk % 400) * 64;
  int tid = threadIdx.x; int rg = tid >> 6; int px = tid & 63;
  int s = s0 + px; int h = s / 160; int w = s - h*160;
  if (rg == 3) {
    for (int c = 0; c < 64; ++c)
      ext[(192 + c)*64 + px] = x[(n*64 + c)*25600 + s];
  } else if (rg == 0) gate_rows<1>(n, h, w, px, ex, fb, ext);
  else if (rg == 1)   gate_rows<3>(n, h, w, px, ex, fb, ext);
  else                gate_rows<5>(n, h, w, px, ex, fb, ext);
  __syncthreads();
  int o0 = __builtin_amdgcn_readfirstlane((tid >> 6) << 4);
  float acc[16];
#pragma unroll
  for (int j = 0; j < 16; ++j) acc[j] = fb[FO_BCOMB + o0 + j];
  const float* wb = fb + FO_WBIGT;
  for (int k = 0; k < 256; ++k) {
    float xv = ext[(k << 6) + px];
    const float* wr = wb + (k << 6) + o0;
#pragma unroll
    for (int j = 0; j < 16; ++j) acc[j] += wr[j] * xv;
  }
#pragma unroll
  for (int j = 0; j < 16; ++j)
    out[(size_t)(n*64 + o0 + j)*25600 + s] = acc[j];
}

// ---------------- launch ----------------
extern "C" void kernel_launch(void* const* d_in, const int* in_sizes, int n_in,
                              void* d_out, int out_size, void* d_ws, size_t ws_size,
                              hipStream_t stream) {
  const float* x     = (const float*)d_in[0];
  const float* exp_w = (const float*)d_in[1];
  const float* exp_b = (const float*)d_in[2];
  const float* res_w = (const float*)d_in[3];
  const float* res_b = (const float*)d_in[4];
  const float* fus_w = (const float*)d_in[5];
  const float* fus_b = (const float*)d_in[6];
  const float* chv_w = (const float*)d_in[7];
  const float* chv_b = (const float*)d_in[8];
  const float* chq_w = (const float*)d_in[9];
  const float* chq_b = (const float*)d_in[10];
  const float* chz_w = (const float*)d_in[11];
  const float* chz_b = (const float*)d_in[12];
  const float* ln_g  = (const float*)d_in[13];
  const float* ln_b  = (const float*)d_in[14];
  const float* spv_w = (const float*)d_in[15];
  const float* spv_b = (const float*)d_in[16];
  const float* spq_w = (const float*)d_in[17];
  const float* spq_b = (const float*)d_in[18];
  float* out = (float*)d_out;

  k_prep<<<393, 256, 0, stream>>>(exp_w, exp_b, res_w, res_b, fus_w, fus_b);
  k_ex<<<6400, 256, 0, stream>>>(x);

  k_logit<1><<<208, 256, 0, stream>>>(chq_w, chq_b);
  k_logit<3><<<288, 256, 0, stream>>>(chq_w, chq_b);
  k_logit<5><<<400, 256, 0, stream>>>(chq_w, chq_b);

  k_xm<1><<<208, 256, 0, stream>>>();
  k_xm<3><<<288, 256, 0, stream>>>();
  k_xm<5><<<400, 256, 0, stream>>>();

  k_bstats<<<560, 256, 0, stream>>>(spq_w, spq_b, spv_w, spv_b);

  k_t<1><<<208, 256, 0, stream>>>();
  k_t<3><<<288, 256, 0, stream>>>();
  k_t<5><<<400, 256, 0, stream>>>();

  k_smap<1><<<208, 256, 0, stream>>>();
  k_smap<3><<<288, 256, 0, stream>>>();
  k_smap<5><<<400, 256, 0, stream>>>();

  k_zln<<<560, 64, 0, stream>>>(chv_w, chv_b, chz_w, chz_b, ln_g, ln_b);

  k_final<<<6400, 256, 0, stream>>>(x, out);
}

// Round 5
// 1257.735 us; speedup vs baseline: 1.4402x; 1.4402x over previous
//
#include <hip/hip_runtime.h>
#include <hip/hip_bf16.h>

typedef __hip_bfloat16 bf16;
#define DEV __device__ __forceinline__

// ---------------- problem constants ----------------
// N=16, C=64, H=W=160, S=25600, expanded channels 192, windows {1,3,5}
// Inputs fp32, output fp32 (confirmed rounds 3/4).

// fp32 scratch layout (offsets in floats)
constexpr int FO_Q     = 0;         // raw softmax logits, per-window concat (1239104)
constexpr int FO_SMAP  = 1239104;   // sigmoid spatial gate (1239104)
constexpr int FO_XM    = 2478208;   // per-(b,c') channel sums (560*64)
constexpr int FO_T     = 2514048;   // per-(b,c') q-weighted sums (560*64)
constexpr int FO_SIGA  = 2549888;   // per-(b,c') channel gate sigmoid(zn) (560*64)
constexpr int FO_G     = 2585728;   // per-(b,c') spatial-branch weights (560*64)
constexpr int FO_BM    = 2621568;   // per-b logit max (560)
constexpr int FO_BINV  = 2622128;   // per-b 1/sum(exp) (560)
constexpr int FO_GB    = 2622688;   // per-b spatial bias term (560)
constexpr int FO_EXPT  = 2623248;   // exp_w transposed [c*192+o] (12288)
constexpr int FO_EXPB  = 2635536;   // exp_b fp32 (192)
constexpr int FO_WBIGT = 2635728;   // combined final weight [k*64+f], k<256 (16384)
constexpr int FO_BCOMB = 2652112;   // combined final bias (64)
constexpr int FB_SIZE  = 2652176;

__device__ unsigned short g_ex_u[78643200]; // 16*192*25600 bf16
__device__ float          g_fb[FB_SIZE];

template<int WIN> struct WP;
template<> struct WP<1> { static constexpr int WI=0, SH=160, KH=160, K=25600, P=1,  B=16,  QOFF=0,      BOFF=0,   CHUNKS=13; };
template<> struct WP<3> { static constexpr int WI=1, SH=53,  KH=54,  K=2916,  P=9,  B=144, QOFF=409600, BOFF=16,  CHUNKS=2;  };
template<> struct WP<5> { static constexpr int WI=2, SH=32,  KH=32,  K=1024,  P=25, B=400, QOFF=829504, BOFF=160, CHUNKS=1;  };

// psa-space walk helpers (used by pass kernels)
template<int WIN> DEV void decomp(int f, int& c, int& kidx, int& p) {
  constexpr int P = WP<WIN>::P, K = WP<WIN>::K;
  int m;
  if constexpr (P == 1) { p = 0; m = f; }
  else { m = f / P; p = f - m * P; }
  c = m / K; kidx = m - c * K;
}

template<int WIN> DEV void stepK(int& c, int& kidx, int& p) {  // f += K
  constexpr int K = WP<WIN>::K, P = WP<WIN>::P;
  if constexpr (P == 1) { kidx += K; }
  else {
    constexpr int KMP = K % P, KDP = K / P;
    if constexpr (KMP == 0) { kidx += KDP; }
    else { p += KMP; if (p >= P) { p -= P; kidx += KDP + 1; } else kidx += KDP; }
  }
  if (kidx >= K) { kidx -= K; ++c; }
}

template<int WIN> DEV int pix(int kidx, int p) {
  constexpr int KH = WP<WIN>::KH, SH = WP<WIN>::SH;
  if constexpr (WIN == 1) return kidx;
  int ki = kidx / KH, kj = kidx - ki * KH;
  int ph = p / WIN,  pw = p - ph * WIN;
  return (ph * SH + ki) * 160 + pw * SH + kj;
}

// ---------------- k_prep ----------------
__global__ __launch_bounds__(256)
void k_prep(const float* __restrict__ exp_w, const float* __restrict__ exp_b,
            const float* __restrict__ res_w, const float* __restrict__ res_b,
            const float* __restrict__ fus_w, const float* __restrict__ fus_b) {
  float* fb = g_fb;
  int gt = blockIdx.x * 256 + threadIdx.x;
  if (gt < 12288) {                       // Wcomb[f][oc] = sum_o fus[f][o]*res[o][oc]
    int oc = gt % 192, f = gt / 192;
    float a = 0.f;
    for (int o = 0; o < 64; ++o)
      a += fus_w[f*64+o] * res_w[o*192+oc];
    fb[FO_WBIGT + oc*64 + f] = a;
  } else if (gt < 16384) {                // rows 192..255: fus_w
    int t2 = gt - 12288; int o = t2 % 64, f = t2 / 64;
    fb[FO_WBIGT + (192+o)*64 + f] = fus_w[f*64+o];
  } else if (gt < 16448) {                // bcomb
    int f = gt - 16384;
    float a = fus_b[f];
    for (int o = 0; o < 64; ++o)
      a += fus_w[f*64+o] * res_b[o];
    fb[FO_BCOMB + f] = a;
  } else if (gt < 28736) {                // expT[c*192+o] = exp_w[o][c]
    int t3 = gt - 16448; int o = t3 % 192, c = t3 / 192;
    fb[FO_EXPT + c*192 + o] = exp_w[o*64+c];
  } else if (gt < 28928) {
    int o = gt - 28736;
    fb[FO_EXPB + o] = exp_b[o];
  } else if (gt < 28928 + 71680) {        // zero xm and t (contiguous)
    fb[FO_XM + gt - 28928] = 0.f;
  }
}

// ---------------- k_ex: ex = conv1x1(x, exp_w, exp_b), bf16 out ----------------
__global__ __launch_bounds__(256)
void k_ex(const float* __restrict__ x) {
  const float* fb = g_fb;
  bf16* ex = (bf16*)g_ex_u;
  __shared__ float xs[64*64];
  int blk = blockIdx.x; int n = blk / 400; int s0 = (blk % 400) * 64;
  int tid = threadIdx.x;
  for (int e = tid; e < 4096; e += 256) {
    int c = e >> 6, px = e & 63;
    xs[e] = x[(n*64 + c)*25600 + s0 + px];
  }
  __syncthreads();
  int px = tid & 63;
  int o0 = __builtin_amdgcn_readfirstlane((tid >> 6) * 48);
  float acc[48];
#pragma unroll
  for (int j = 0; j < 48; ++j) acc[j] = fb[FO_EXPB + o0 + j];
  const float* wT = fb + FO_EXPT;
  for (int c = 0; c < 64; ++c) {
    float xv = xs[(c << 6) + px];
    const float* wr = wT + c*192 + o0;
#pragma unroll
    for (int j = 0; j < 48; ++j) acc[j] += wr[j] * xv;
  }
  bf16* eo = ex + (size_t)(n*192 + o0)*25600 + s0 + px;
#pragma unroll
  for (int j = 0; j < 48; ++j) eo[(size_t)j*25600] = __float2bfloat16(acc[j]);
}

// ---------------- k_pass1: fused logit + xm (one ex read) ----------------
// 4 waves; wave w owns channels [16w,16w+16); all waves share the same sp.
template<int WIN> __global__ __launch_bounds__(256)
void k_pass1(const float* __restrict__ chq_w, const float* __restrict__ chq_b) {
  using W = WP<WIN>;
  constexpr int K = W::K, P = W::P, CK = 64*K, WI = W::WI, QOFF = W::QOFF,
                BOFF = W::BOFF, CH = W::CHUNKS;
  float* fb = g_fb;
  const bf16* ex = (const bf16*)g_ex_u;
  __shared__ float dots[256];
  int tid = threadIdx.x, lane = tid & 63; int c0 = (tid >> 6) * 16;
  int blk = blockIdx.x; int bi = blk / CH; int ch = blk - bi*CH;
  int n = bi / P, bl = bi - n*P; int bg = BOFF + bi;
  int send = ((ch+1)*2048 < K) ? (ch+1)*2048 : K;
  const bf16* exn = ex + (size_t)(n*192 + WI*64)*25600;
  float* qout = fb + FO_Q + QOFF + (size_t)bi*K;
  float wqr[16];
#pragma unroll
  for (int j = 0; j < 16; ++j) wqr[j] = chq_w[c0 + j];
  float wqb = chq_b[0];
  float part[16];
#pragma unroll
  for (int j = 0; j < 16; ++j) part[j] = 0.f;
  for (int spb = ch*2048; spb < send; spb += 64) {
    int sp = spb + lane;
    float dot = 0.f;
    if (sp < send) {
      int f = bl*CK + c0*K + sp;
      int c, kidx, p; decomp<WIN>(f, c, kidx, p);
#pragma unroll
      for (int j = 0; j < 16; ++j) {
        float v = __bfloat162float(exn[c*25600 + pix<WIN>(kidx, p)]);
        part[j] += v;
        dot += wqr[j] * v;
        stepK<WIN>(c, kidx, p);
      }
    }
    dots[tid] = dot;
    __syncthreads();
    if (tid < 64 && spb + tid < send)
      qout[spb + tid] = dots[tid] + dots[64+tid] + dots[128+tid] + dots[192+tid] + wqb;
    __syncthreads();
  }
#pragma unroll
  for (int j = 0; j < 16; ++j) {
    float v = part[j];
    for (int off = 32; off; off >>= 1) v += __shfl_xor(v, off, 64);
    if (lane == 0) atomicAdd(&fb[FO_XM + bg*64 + c0 + j], v);
  }
}

// ---------------- k_bstats: per-b softmax stats + spatial branch ----------------
__global__ __launch_bounds__(256)
void k_bstats(const float* __restrict__ spq_w, const float* __restrict__ spq_b,
              const float* __restrict__ spv_w, const float* __restrict__ spv_b) {
  float* fb = g_fb;
  __shared__ float red[256]; __shared__ float sqs[32]; __shared__ float swq[32];
  int bg = blockIdx.x, tid = threadIdx.x;
  int Kk, qo, bi;
  if (bg < 16)       { Kk = 25600; qo = 0;      bi = bg;       }
  else if (bg < 160) { Kk = 2916;  qo = 409600; bi = bg - 16;  }
  else               { Kk = 1024;  qo = 829504; bi = bg - 160; }
  const float* lg = fb + FO_Q + qo + (size_t)bi*Kk;
  float m = -1e30f;
  for (int s = tid; s < Kk; s += 256) m = fmaxf(m, lg[s]);
  red[tid] = m; __syncthreads();
  for (int st = 128; st; st >>= 1) { if (tid < st) red[tid] = fmaxf(red[tid], red[tid+st]); __syncthreads(); }
  float M = red[0]; __syncthreads();
  float ss = 0.f;
  for (int s = tid; s < Kk; s += 256) ss += __expf(lg[s] - M);
  red[tid] = ss; __syncthreads();
  for (int st = 128; st; st >>= 1) { if (tid < st) red[tid] += red[tid+st]; __syncthreads(); }
  if (tid == 0) { fb[FO_BM + bg] = M; fb[FO_BINV + bg] = 1.f / red[0]; }
  const float* xm_b = fb + FO_XM + bg*64;
  float rK = 1.f / (float)Kk;
  if (tid < 32) {
    float a = spq_b[tid];
    for (int c = 0; c < 64; ++c)
      a += spq_w[tid*64 + c] * (xm_b[c] * rK);
    sqs[tid] = a;
  }
  __syncthreads();
  if (tid == 0) {
    float mx = -1e30f;
    for (int o = 0; o < 32; ++o) mx = fmaxf(mx, sqs[o]);
    float z = 0.f;
    for (int o = 0; o < 32; ++o) { float e = __expf(sqs[o] - mx); swq[o] = e; z += e; }
    float rz = 1.f / z;
    for (int o = 0; o < 32; ++o) swq[o] *= rz;
  }
  __syncthreads();
  if (tid < 64) {
    float a = 0.f;
    for (int o = 0; o < 32; ++o) a += swq[o] * spv_w[o*64 + tid];
    fb[FO_G + bg*64 + tid] = a;
  }
  if (tid == 64) {
    float gb = 0.f;
    for (int o = 0; o < 32; ++o) gb += swq[o] * spv_b[o];
    fb[FO_GB + bg] = gb;
  }
}

// ---------------- k_pass2: fused t + smap (one ex read) ----------------
template<int WIN> __global__ __launch_bounds__(256)
void k_pass2() {
  using W = WP<WIN>;
  constexpr int K = W::K, P = W::P, CK = 64*K, WI = W::WI, QOFF = W::QOFF,
                BOFF = W::BOFF, CH = W::CHUNKS;
  float* fb = g_fb;
  const bf16* ex = (const bf16*)g_ex_u;
  __shared__ float dots[256];
  int tid = threadIdx.x, lane = tid & 63; int c0 = (tid >> 6) * 16;
  int blk = blockIdx.x; int bi = blk / CH; int ch = blk - bi*CH;
  int n = bi / P, bl = bi - n*P; int bg = BOFF + bi;
  int send = ((ch+1)*2048 < K) ? (ch+1)*2048 : K;
  const bf16* exn = ex + (size_t)(n*192 + WI*64)*25600;
  const float* qin = fb + FO_Q + QOFF + (size_t)bi*K;
  float* so = fb + FO_SMAP + QOFF + (size_t)bi*K;
  float M = fb[FO_BM + bg], inv = fb[FO_BINV + bg];
  float gsr[16];
#pragma unroll
  for (int j = 0; j < 16; ++j) gsr[j] = fb[FO_G + bg*64 + c0 + j];
  float gbs = fb[FO_GB + bg];
  float part[16];
#pragma unroll
  for (int j = 0; j < 16; ++j) part[j] = 0.f;
  for (int spb = ch*2048; spb < send; spb += 64) {
    int sp = spb + lane;
    float dot = 0.f;
    if (sp < send) {
      float qv = __expf(qin[sp] - M) * inv;
      int f = bl*CK + c0*K + sp;
      int c, kidx, p; decomp<WIN>(f, c, kidx, p);
#pragma unroll
      for (int j = 0; j < 16; ++j) {
        float v = __bfloat162float(exn[c*25600 + pix<WIN>(kidx, p)]);
        part[j] += qv * v;
        dot += gsr[j] * v;
        stepK<WIN>(c, kidx, p);
      }
    }
    dots[tid] = dot;
    __syncthreads();
    if (tid < 64 && spb + tid < send) {
      float d = dots[tid] + dots[64+tid] + dots[128+tid] + dots[192+tid] + gbs;
      so[spb + tid] = 1.f / (1.f + __expf(-d));
    }
    __syncthreads();
  }
#pragma unroll
  for (int j = 0; j < 16; ++j) {
    float v = part[j];
    for (int off = 32; off; off >>= 1) v += __shfl_xor(v, off, 64);
    if (lane == 0) atomicAdd(&fb[FO_T + bg*64 + c0 + j], v);
  }
}

// ---------------- k_zln: wz -> z -> LayerNorm -> sigA ----------------
__global__ __launch_bounds__(64)
void k_zln(const float* __restrict__ chv_w, const float* __restrict__ chv_b,
           const float* __restrict__ chz_w, const float* __restrict__ chz_b,
           const float* __restrict__ ln_g,  const float* __restrict__ ln_b) {
  float* fb = g_fb;
  __shared__ float wzs[32]; __shared__ float zsh[64]; __shared__ float mom[2];
  int bg = blockIdx.x, tid = threadIdx.x;
  const float* t_b = fb + FO_T + bg*64;
  if (tid < 32) {
    float a = chv_b[tid];
    for (int c = 0; c < 64; ++c)
      a += chv_w[tid*64 + c] * t_b[c];
    wzs[tid] = a;
  }
  __syncthreads();
  float zv = chz_b[tid];
  for (int o = 0; o < 32; ++o)
    zv += chz_w[tid*32 + o] * wzs[o];
  zsh[tid] = zv;
  __syncthreads();
  if (tid == 0) {
    float mu = 0.f;
    for (int j = 0; j < 64; ++j) mu += zsh[j];
    mu *= (1.f/64.f);
    float m2 = 0.f;
    for (int j = 0; j < 64; ++j) { float d = zsh[j] - mu; m2 += d*d; }
    m2 *= (1.f/64.f);
    mom[0] = mu; mom[1] = rsqrtf(m2 + 1e-5f);
  }
  __syncthreads();
  float zn = (zv - mom[0]) * mom[1] * ln_g[tid] + ln_b[tid];
  fb[FO_SIGA + bg*64 + tid] = 1.f / (1.f + __expf(-zn));
}

// ---------------- k_final: gates -> cat(bf16 LDS) -> fused double conv ------
// Gate algebra (per window): f = c*K*P + base0, base0 = q*K + s0 =>
//   sp = s0 (const in c), cpfull = c*P + q, siga idx = cpfull,
//   smap idx = (cpfull>>6)*K + s0. No divisions in the c-loop.
template<int WIN> DEV void gate_rows(int n, int h, int w, int px,
                                     const bf16* __restrict__ ex,
                                     const float* __restrict__ fb, bf16* ext) {
  using W = WP<WIN>;
  constexpr int SH = W::SH, KH = W::KH, K = W::K, P = W::P, WI = W::WI,
                QOFF = W::QOFF, BOFF = W::BOFF;
  int s = h*160 + w;
  const float* siga = fb + FO_SIGA + (size_t)(BOFF + n*P)*64;
  const float* smap = fb + FO_SMAP + QOFF + (size_t)(n*P)*K;
  const bf16* exr = ex + (size_t)(n*192 + WI*64)*25600 + s;
  if constexpr (WIN == 1) {
    float sm = smap[s];
    for (int c = 0; c < 64; ++c) {
      float exv = __bfloat162float(exr[(size_t)c*25600]);
      ext[(WI*64 + c)*64 + px] = __float2bfloat16(exv * (1.f + siga[c] + sm));
    }
  } else {
    int phmin = (h >= KH) ? (h - KH)/SH + 1 : 0;
    int phmax = (WIN-1 < h/SH) ? WIN-1 : h/SH;
    int pwmin = (w >= KH) ? (w - KH)/SH + 1 : 0;
    int pwmax = (WIN-1 < w/SH) ? WIN-1 : w/SH;
    int cpf[4]; int s0s[4]; int np = 0;
    for (int ph = phmin; ph <= phmax; ++ph)
      for (int pw = pwmin; pw <= pwmax; ++pw) {
        int ki = h - ph*SH, kj = w - pw*SH;
        unsigned base0 = (unsigned)((ki*KH + kj)*P + ph*WIN + pw);
        unsigned q = base0 / (unsigned)K;
        cpf[np] = (int)q; s0s[np] = (int)(base0 - q*(unsigned)K); ++np;
      }
    float rc = 1.f / (float)np;
    for (int c = 0; c < 64; ++c) {
      float gsum = 0.f;
#pragma unroll
      for (int t = 0; t < 4; ++t) {
        if (t < np) {
          int cf = cpf[t];
          gsum += siga[cf] + smap[(cf >> 6)*K + s0s[t]];
          cpf[t] = cf + P;
        }
      }
      float exv = __bfloat162float(exr[(size_t)c*25600]);
      ext[(WI*64 + c)*64 + px] = __float2bfloat16(exv * (1.f + gsum * rc));
    }
  }
}

__global__ __launch_bounds__(256)
void k_final(const float* __restrict__ x, float* __restrict__ out) {
  const float* fb = g_fb;
  const bf16* ex = (const bf16*)g_ex_u;
  __shared__ bf16 ext[256*64];   // 32 KB (bf16 cat tile)
  int blk = blockIdx.x; int n = blk / 400; int s0 = (blk % 400) * 64;
  int tid = threadIdx.x; int rg = tid >> 6; int px = tid & 63;
  int s = s0 + px; int h = s / 160; int w = s - h*160;
  if (rg == 3) {
    for (int c = 0; c < 64; ++c)
      ext[(192 + c)*64 + px] = __float2bfloat16(x[(n*64 + c)*25600 + s]);
  } else if (rg == 0) gate_rows<1>(n, h, w, px, ex, fb, ext);
  else if (rg == 1)   gate_rows<3>(n, h, w, px, ex, fb, ext);
  else                gate_rows<5>(n, h, w, px, ex, fb, ext);
  __syncthreads();
  int o0 = __builtin_amdgcn_readfirstlane((tid >> 6) << 4);
  float acc[16];
#pragma unroll
  for (int j = 0; j < 16; ++j) acc[j] = fb[FO_BCOMB + o0 + j];
  const float* wb = fb + FO_WBIGT;
  for (int k = 0; k < 256; ++k) {
    float xv = __bfloat162float(ext[(k << 6) + px]);
    const float* wr = wb + (k << 6) + o0;
#pragma unroll
    for (int j = 0; j < 16; ++j) acc[j] += wr[j] * xv;
  }
#pragma unroll
  for (int j = 0; j < 16; ++j)
    out[(size_t)(n*64 + o0 + j)*25600 + s] = acc[j];
}

// ---------------- launch ----------------
extern "C" void kernel_launch(void* const* d_in, const int* in_sizes, int n_in,
                              void* d_out, int out_size, void* d_ws, size_t ws_size,
                              hipStream_t stream) {
  const float* x     = (const float*)d_in[0];
  const float* exp_w = (const float*)d_in[1];
  const float* exp_b = (const float*)d_in[2];
  const float* res_w = (const float*)d_in[3];
  const float* res_b = (const float*)d_in[4];
  const float* fus_w = (const float*)d_in[5];
  const float* fus_b = (const float*)d_in[6];
  const float* chv_w = (const float*)d_in[7];
  const float* chv_b = (const float*)d_in[8];
  const float* chq_w = (const float*)d_in[9];
  const float* chq_b = (const float*)d_in[10];
  const float* chz_w = (const float*)d_in[11];
  const float* chz_b = (const float*)d_in[12];
  const float* ln_g  = (const float*)d_in[13];
  const float* ln_b  = (const float*)d_in[14];
  const float* spv_w = (const float*)d_in[15];
  const float* spv_b = (const float*)d_in[16];
  const float* spq_w = (const float*)d_in[17];
  const float* spq_b = (const float*)d_in[18];
  float* out = (float*)d_out;

  k_prep<<<393, 256, 0, stream>>>(exp_w, exp_b, res_w, res_b, fus_w, fus_b);
  k_ex<<<6400, 256, 0, stream>>>(x);

  k_pass1<1><<<208, 256, 0, stream>>>(chq_w, chq_b);
  k_pass1<3><<<288, 256, 0, stream>>>(chq_w, chq_b);
  k_pass1<5><<<400, 256, 0, stream>>>(chq_w, chq_b);

  k_bstats<<<560, 256, 0, stream>>>(spq_w, spq_b, spv_w, spv_b);

  k_pass2<1><<<208, 256, 0, stream>>>();
  k_pass2<3><<<288, 256, 0, stream>>>();
  k_pass2<5><<<400, 256, 0, stream>>>();

  k_zln<<<560, 64, 0, stream>>>(chv_w, chv_b, chz_w, chz_b, ln_g, ln_b);

  k_final<<<6400, 256, 0, stream>>>(x, out);
}